// Round 7
// baseline (338.379 us; speedup 1.0000x reference)
//
#include <hip/hip_runtime.h>
#include <hip/hip_bf16.h>

// LSTM: B=16384, T=5, IN=11, H=512. Output = final cell state c [B,H] fp32.
//
// R7 = R6 (W read once per block per step, frag-ordered LDS, 16 waves/CU)
// made spill-free. R6's allocator split 64 arch + 64 AGPR and the arch side
// (cacc 32 + B 16 + A 4 + addr ~15 = 67) spilled ~90 MB of scratch, which
// also thrashed the per-XCD L2 the B-stream lives in. Fixes:
//  - cacc (8 x f32x4) pinned into AGPRs via empty-asm "+a" constraints:
//    AGPR = acc 64 + cacc 32 = 96, arch = B 16 + A 4 + ptrs ~10 <= 32.
//  - address diet: one scatter base per ji (all 16 h ds_write_b16 use
//    immediate offsets); B loads via one stepped pointer + imm offsets.
//  - ks-loop stays `#pragma unroll 1` (R4), no manual pipeline (R5 lesson).

#define HID   512
#define KSN   17                    // K = 544 = 512 h + 11 x + 1 bias + 20 pad
#define ROWS  64
#define NTHR  1024                  // 16 waves
#define HB    (KSN * 4 * 64 * 8)    // halves per frag-ordered h buffer = 34816
#define SMEM_HALFS (2 * HB + 64 * 56)
#define SMEM_BYTES (SMEM_HALFS * 2) // 146432 B -> 1 block/CU

typedef _Float16 f16x8 __attribute__((ext_vector_type(8)));
typedef float f32x4 __attribute__((ext_vector_type(4)));

__device__ __forceinline__ float sigf(float x) {
    return 1.0f / (1.0f + __expf(-x));
}
__device__ __forceinline__ float tanh_fast(float x) {
    return 1.0f - 2.0f / (1.0f + __expf(2.0f * x));
}

// ---------------- prologue: pack W into B-fragment-ordered fp16 tiles -------
// Fragment f = (j*KSN + ks)*4 + g  (g innermost). Lane l holds
// W[col = g*512 + j*16 + (l&15)][k = ks*32 + (l>>4)*8 .. +7], 16 B/lane.
__global__ void pack_w(const float* __restrict__ Wih, const float* __restrict__ Whh,
                       const float* __restrict__ bih, const float* __restrict__ bhh,
                       _Float16* __restrict__ Wt) {
    int tid  = blockIdx.x * 256 + threadIdx.x;
    int frag = tid >> 6;
    int lane = tid & 63;
    if (frag >= 32 * KSN * 4) return;
    int g  = frag & 3;
    int ks = (frag >> 2) % KSN;
    int j  = frag / (4 * KSN);
    int col = g * 512 + j * 16 + (lane & 15);
    int kb  = ks * 32 + ((lane >> 4) << 3);
    _Float16 v[8];
#pragma unroll
    for (int q = 0; q < 8; q++) {
        int k = kb + q;
        float x;
        if (k < 512)      x = Whh[col * 512 + k];
        else if (k < 523) x = Wih[col * 11 + (k - 512)];
        else if (k == 523) x = bih[col] + bhh[col];
        else              x = 0.0f;
        v[q] = (_Float16)x;
    }
    *(f16x8*)(Wt + (size_t)frag * 512 + lane * 8) = *(const f16x8*)v;
}

// ---------------- one recurrent step ----------------------------------------
// Wave w: all 64 rows (rt 0..3), col-quads j = 2w, 2w+1, 4 gates.
// h buffers A-frag ordered: f16x8 unit index = (ks*4 + rt)*64 + lane.
// cacc: 8 chunks of f32x4; chunk ji*4+rt, element r. Pinned to AGPR by caller.
template <int KS0, bool WRITE_H>
__device__ __forceinline__ void run_step(const _Float16* __restrict__ cur,
                                         _Float16* __restrict__ nxt,
                                         const _Float16* __restrict__ Wt,
                                         f32x4* __restrict__ cacc,
                                         const int wave, const int lane) {
    const int c  = lane & 15;
    const int kq = lane >> 4;
    const f16x8* __restrict__ cur8 = (const f16x8*)cur;
#pragma unroll
    for (int ji = 0; ji < 2; ji++) {
        const int j = wave * 2 + ji;
        const f16x8* __restrict__ bp =
            (const f16x8*)Wt + ((size_t)j * KSN + KS0) * 256 + lane;
        const f16x8* __restrict__ ap = cur8 + KS0 * 256 + lane;
        // scatter base for h-writes of this ji (all 16 writes use imm offsets)
        _Float16* __restrict__ hw = nxt + (j >> 1) * 2048
            + (kq * 4 + 16 * (((j & 1) << 1) | (c >> 3))) * 8 + (c & 7);

        f32x4 acc[4][4];                                   // [row-tile][gate]
#pragma unroll
        for (int rt = 0; rt < 4; rt++)
#pragma unroll
            for (int g = 0; g < 4; g++) {
                f32x4 z = {0.f, 0.f, 0.f, 0.f};
                acc[rt][g] = z;
            }

#pragma unroll 1                        // REAL loop (anti-spill, R4 lesson)
        for (int ks = KS0; ks < KSN; ks++) {
            f16x8 B0 = bp[0 * 64];
            f16x8 B1 = bp[1 * 64];
            f16x8 B2 = bp[2 * 64];
            f16x8 B3 = bp[3 * 64];
#pragma unroll
            for (int rt = 0; rt < 4; rt++) {
                f16x8 A = ap[rt * 64];  // one A live at a time
                acc[rt][0] = __builtin_amdgcn_mfma_f32_16x16x32_f16(A, B0, acc[rt][0], 0, 0, 0);
                acc[rt][1] = __builtin_amdgcn_mfma_f32_16x16x32_f16(A, B1, acc[rt][1], 0, 0, 0);
                acc[rt][2] = __builtin_amdgcn_mfma_f32_16x16x32_f16(A, B2, acc[rt][2], 0, 0, 0);
                acc[rt][3] = __builtin_amdgcn_mfma_f32_16x16x32_f16(A, B3, acc[rt][3], 0, 0, 0);
            }
            bp += 256;
            ap += 256;
        }

        // gate nonlinearities; C/D layout: col = lane&15, row = (lane>>4)*4+r
#pragma unroll
        for (int rt = 0; rt < 4; rt++) {
            f32x4 cv = cacc[ji * 4 + rt];
#pragma unroll
            for (int r = 0; r < 4; r++) {
                float ig = acc[rt][0][r];
                float fg = acc[rt][1][r];
                float gg = acc[rt][2][r];
                float og = acc[rt][3][r];
                float cn = sigf(fg) * cv[r] + sigf(ig) * tanh_fast(gg);
                cv[r] = cn;
                if (WRITE_H) {
                    float hn = sigf(og) * tanh_fast(cn);
                    hw[rt * 512 + r * 8] = (_Float16)hn;   // imm-offset ds_write
                }
            }
            cacc[ji * 4 + rt] = cv;
            asm volatile("" : "+a"(cacc[ji * 4 + rt]));    // keep cacc in AGPRs
        }
    }
}

// x_t (11 elems) into the ks=16 frag region of a buffer (A-frag layout).
__device__ __forceinline__ void xfill(_Float16* __restrict__ nxt,
                                      const _Float16* __restrict__ xlds,
                                      int step, int tid) {
    for (int i = tid; i < 64 * 11; i += NTHR) {
        int row = i / 11, xi = i - row * 11;
        int idx = ((16 * 4 + (row >> 4)) * 64 + ((row & 15) + 16 * (xi >> 3))) * 8
                  + (xi & 7);
        nxt[idx] = xlds[row * 56 + step * 11 + xi];
    }
}

// ---------------- main persistent kernel ------------------------------------
__global__ __launch_bounds__(NTHR, 4)
void lstm_main(const float* __restrict__ ts,
               const _Float16* __restrict__ Wt,
               float* __restrict__ out) {
    extern __shared__ _Float16 smem[];
    _Float16* buf0 = smem;             // frag-ordered h buffers
    _Float16* buf1 = smem + HB;
    _Float16* xlds = smem + 2 * HB;    // [64][56] fp16 staged ts rows
    const int tid  = threadIdx.x;
    const int lane = tid & 63;
    const int wave = tid >> 6;         // 0..15
    const int b0   = blockIdx.x * ROWS;

    // zero both h buffers (covers all pad columns)
    {
        f16x8 z = {(_Float16)0, (_Float16)0, (_Float16)0, (_Float16)0,
                   (_Float16)0, (_Float16)0, (_Float16)0, (_Float16)0};
        for (int i = tid * 8; i < 2 * HB; i += NTHR * 8)
            *(f16x8*)(smem + i) = z;
    }
    // stage this block's time_series rows (coalesced) as fp16
    for (int i = tid; i < 64 * 55; i += NTHR) {
        int row = i / 55, e = i - row * 55;
        xlds[row * 56 + e] = (_Float16)ts[(size_t)(b0 + row) * 55 + e];
    }
    __syncthreads();
    // bias column (k=523 -> ks16, kq2=1, q=3) = 1.0 in both buffers; x_0 -> buf0
    if (tid < 128) {
        int bsel = tid >> 6, row = tid & 63;
        int idx = ((16 * 4 + (row >> 4)) * 64 + ((row & 15) + 16)) * 8 + 3;
        (bsel ? buf1 : buf0)[idx] = (_Float16)1.0f;
    }
    xfill(buf0, xlds, 0, tid);
    __syncthreads();

    f32x4 cacc[8];
#pragma unroll
    for (int i = 0; i < 8; i++) {
        f32x4 z = {0.f, 0.f, 0.f, 0.f};
        cacc[i] = z;
        asm volatile("" : "+a"(cacc[i]));   // establish AGPR home
    }

    // t = 0: h == 0, only the x/bias K-step contributes
    run_step<16, true>(buf0, buf1, Wt, cacc, wave, lane);
    xfill(buf1, xlds, 1, tid);
    __syncthreads();

    for (int t = 1; t < 4; t++) {
        _Float16* cur = (t & 1) ? buf1 : buf0;
        _Float16* nxt = (t & 1) ? buf0 : buf1;
        run_step<0, true>(cur, nxt, Wt, cacc, wave, lane);
        xfill(nxt, xlds, t + 1, tid);
        __syncthreads();
    }
    // t = 4: no h write needed
    run_step<0, false>(buf0, buf1, Wt, cacc, wave, lane);

    // write final c
    const int c = lane & 15, kq = lane >> 4;
#pragma unroll
    for (int ji = 0; ji < 2; ji++) {
        const int j = wave * 2 + ji;
#pragma unroll
        for (int rt = 0; rt < 4; rt++) {
            f32x4 cv = cacc[ji * 4 + rt];
#pragma unroll
            for (int r = 0; r < 4; r++)
                out[(size_t)(b0 + rt * 16 + kq * 4 + r) * HID + j * 16 + c] = cv[r];
        }
    }
}

extern "C" void kernel_launch(void* const* d_in, const int* in_sizes, int n_in,
                              void* d_out, int out_size, void* d_ws, size_t ws_size,
                              hipStream_t stream) {
    const float* ts  = (const float*)d_in[0];
    const float* Wih = (const float*)d_in[1];
    const float* Whh = (const float*)d_in[2];
    const float* bih = (const float*)d_in[3];
    const float* bhh = (const float*)d_in[4];
    float* out       = (float*)d_out;
    _Float16* Wt     = (_Float16*)d_ws;   // 2176 frags x 1 KB = 2,228,224 B

    (void)in_sizes; (void)n_in; (void)out_size; (void)ws_size;

    hipFuncSetAttribute(reinterpret_cast<const void*>(lstm_main),
                        hipFuncAttributeMaxDynamicSharedMemorySize, SMEM_BYTES);

    pack_w<<<544, 256, 0, stream>>>(Wih, Whh, bih, bhh, Wt);
    lstm_main<<<256, NTHR, SMEM_BYTES, stream>>>(ts, Wt, out);
}

// Round 8
// 261.833 us; speedup vs baseline: 1.2923x; 1.2923x over previous
//
#include <hip/hip_runtime.h>
#include <hip/hip_bf16.h>

// LSTM: B=16384, T=5, IN=11, H=512. Output = final cell state c [B,H] fp32.
//
// R8: register-pressure fix by GATE-PAIRED PASSES (R6/R7 post-mortems: at 16
// waves the 128-reg budget cannot hold acc 64 + cacc 32 + ~30 transients;
// both the plain version (R6) and AGPR-pinned version (R7) spilled).
//  - W re-packed with gate order (i,g,f,o). Each (wave, ji) does two passes
//    over K: pass A = gates {i,g} -> acc[4][2] (32) reduced immediately to
//    ig = sig(i)*tanh(g) (16); pass B = gates {f,o} -> c,h update.
//    Peak live ~100 regs < 128. W still read exactly once per block per step.
//  - everything else proven in R4-R6 kept: 16 waves (4/SIMD TLP), frag-
//    ordered h in LDS (conflict-free ds_read_b128), `#pragma unroll 1`
//    K-loops, no manual pipelining, no asm pinning.

#define HID   512
#define KSN   17                    // K = 544 = 512 h + 11 x + 1 bias + 20 pad
#define ROWS  64
#define NTHR  1024                  // 16 waves
#define HB    (KSN * 4 * 64 * 8)    // halves per frag-ordered h buffer = 34816
#define SMEM_HALFS (2 * HB + 64 * 56)
#define SMEM_BYTES (SMEM_HALFS * 2) // 146432 B -> 1 block/CU

typedef _Float16 f16x8 __attribute__((ext_vector_type(8)));
typedef float f32x4 __attribute__((ext_vector_type(4)));

__device__ __forceinline__ float sigf(float x) {
    return 1.0f / (1.0f + __expf(-x));
}
__device__ __forceinline__ float tanh_fast(float x) {
    return 1.0f - 2.0f / (1.0f + __expf(2.0f * x));
}

// ---------------- prologue: pack W into B-fragment-ordered fp16 tiles -------
// Fragment f = (j*KSN + ks)*4 + gp, gp in PACKED gate order (i,g,f,o) so a
// pass's two gates are contiguous (2 KB). Lane l holds
// W[col = orig_gate(gp)*512 + j*16 + (l&15)][k = ks*32 + (l>>4)*8 .. +7].
__global__ void pack_w(const float* __restrict__ Wih, const float* __restrict__ Whh,
                       const float* __restrict__ bih, const float* __restrict__ bhh,
                       _Float16* __restrict__ Wt) {
    int tid  = blockIdx.x * 256 + threadIdx.x;
    int frag = tid >> 6;
    int lane = tid & 63;
    if (frag >= 32 * KSN * 4) return;
    int gp = frag & 3;
    int ks = (frag >> 2) % KSN;
    int j  = frag / (4 * KSN);
    // packed order (i,g,f,o) -> original torch gate blocks (i,f,g,o)
    const int gmap[4] = {0, 2, 1, 3};
    int col = gmap[gp] * 512 + j * 16 + (lane & 15);
    int kb  = ks * 32 + ((lane >> 4) << 3);
    _Float16 v[8];
#pragma unroll
    for (int q = 0; q < 8; q++) {
        int k = kb + q;
        float x;
        if (k < 512)      x = Whh[col * 512 + k];
        else if (k < 523) x = Wih[col * 11 + (k - 512)];
        else if (k == 523) x = bih[col] + bhh[col];
        else              x = 0.0f;
        v[q] = (_Float16)x;
    }
    *(f16x8*)(Wt + (size_t)frag * 512 + lane * 8) = *(const f16x8*)v;
}

// ---------------- one recurrent step ----------------------------------------
// Wave w: 64 rows (rt 0..3), col-quads j = 2w+ji (ji 0..1), per ji two
// gate-paired passes (A: i,g -> ig; B: f,o -> c,h).
// h buffers A-frag ordered: f16x8 unit index = (ks*4 + rt)*64 + lane.
template <int KS0, bool WRITE_H>
__device__ __forceinline__ void run_step(const _Float16* __restrict__ cur,
                                         _Float16* __restrict__ nxt,
                                         const _Float16* __restrict__ Wt,
                                         f32x4* __restrict__ cacc,
                                         const int wave, const int lane) {
    const int c  = lane & 15;
    const int kq = lane >> 4;
    const f16x8* __restrict__ cur8 = (const f16x8*)cur;
#pragma unroll
    for (int ji = 0; ji < 2; ji++) {
        const int j = wave * 2 + ji;
        // scatter base for h-writes of this ji (all writes use imm offsets)
        _Float16* __restrict__ hw = nxt + (j >> 1) * 2048
            + (kq * 4 + 16 * (((j & 1) << 1) | (c >> 3))) * 8 + (c & 7);
        f32x4 ig[4];                           // sig(i)*tanh(g) per row-tile

#pragma unroll
        for (int pass = 0; pass < 2; pass++) {
            const f16x8* __restrict__ bp = (const f16x8*)Wt
                + (((size_t)j * KSN + KS0) * 4 + pass * 2) * 64 + lane;
            const f16x8* __restrict__ ap = cur8 + KS0 * 256 + lane;
            f32x4 acc[4][2];                   // [row-tile][gate-of-pair]
#pragma unroll
            for (int rt = 0; rt < 4; rt++)
#pragma unroll
                for (int g = 0; g < 2; g++) {
                    f32x4 z = {0.f, 0.f, 0.f, 0.f};
                    acc[rt][g] = z;
                }

#pragma unroll 1                    // REAL loop (anti-spill, R4 lesson)
            for (int ks = KS0; ks < KSN; ks++) {
                f16x8 B0 = bp[0];
                f16x8 B1 = bp[64];
#pragma unroll
                for (int rt = 0; rt < 4; rt++) {
                    f16x8 A = ap[rt * 64];
                    acc[rt][0] = __builtin_amdgcn_mfma_f32_16x16x32_f16(A, B0, acc[rt][0], 0, 0, 0);
                    acc[rt][1] = __builtin_amdgcn_mfma_f32_16x16x32_f16(A, B1, acc[rt][1], 0, 0, 0);
                }
                bp += 256;
                ap += 256;
            }

            if (pass == 0) {
                // reduce i,g -> ig, freeing acc before pass B
#pragma unroll
                for (int rt = 0; rt < 4; rt++)
#pragma unroll
                    for (int r = 0; r < 4; r++)
                        ig[rt][r] = sigf(acc[rt][0][r]) * tanh_fast(acc[rt][1][r]);
            } else {
                // f,o: update c, write h
#pragma unroll
                for (int rt = 0; rt < 4; rt++) {
                    f32x4 cv = cacc[ji * 4 + rt];
#pragma unroll
                    for (int r = 0; r < 4; r++) {
                        float cn = sigf(acc[rt][0][r]) * cv[r] + ig[rt][r];
                        cv[r] = cn;
                        if (WRITE_H) {
                            float hn = sigf(acc[rt][1][r]) * tanh_fast(cn);
                            hw[rt * 512 + r * 8] = (_Float16)hn;
                        }
                    }
                    cacc[ji * 4 + rt] = cv;
                }
            }
        }
    }
}

// x_t (11 elems) into the ks=16 frag region of a buffer (A-frag layout).
__device__ __forceinline__ void xfill(_Float16* __restrict__ nxt,
                                      const _Float16* __restrict__ xlds,
                                      int step, int tid) {
    for (int i = tid; i < 64 * 11; i += NTHR) {
        int row = i / 11, xi = i - row * 11;
        int idx = ((16 * 4 + (row >> 4)) * 64 + ((row & 15) + 16 * (xi >> 3))) * 8
                  + (xi & 7);
        nxt[idx] = xlds[row * 56 + step * 11 + xi];
    }
}

// ---------------- main persistent kernel ------------------------------------
__global__ __launch_bounds__(NTHR, 4)
void lstm_main(const float* __restrict__ ts,
               const _Float16* __restrict__ Wt,
               float* __restrict__ out) {
    extern __shared__ _Float16 smem[];
    _Float16* buf0 = smem;             // frag-ordered h buffers
    _Float16* buf1 = smem + HB;
    _Float16* xlds = smem + 2 * HB;    // [64][56] fp16 staged ts rows
    const int tid  = threadIdx.x;
    const int lane = tid & 63;
    const int wave = tid >> 6;         // 0..15
    const int b0   = blockIdx.x * ROWS;

    // zero both h buffers (covers all pad columns)
    {
        f16x8 z = {(_Float16)0, (_Float16)0, (_Float16)0, (_Float16)0,
                   (_Float16)0, (_Float16)0, (_Float16)0, (_Float16)0};
        for (int i = tid * 8; i < 2 * HB; i += NTHR * 8)
            *(f16x8*)(smem + i) = z;
    }
    // stage this block's time_series rows (coalesced) as fp16
    for (int i = tid; i < 64 * 55; i += NTHR) {
        int row = i / 55, e = i - row * 55;
        xlds[row * 56 + e] = (_Float16)ts[(size_t)(b0 + row) * 55 + e];
    }
    __syncthreads();
    // bias column (k=523 -> ks16, kq2=1, q=3) = 1.0 in both buffers; x_0 -> buf0
    if (tid < 128) {
        int bsel = tid >> 6, row = tid & 63;
        int idx = ((16 * 4 + (row >> 4)) * 64 + ((row & 15) + 16)) * 8 + 3;
        (bsel ? buf1 : buf0)[idx] = (_Float16)1.0f;
    }
    xfill(buf0, xlds, 0, tid);
    __syncthreads();

    f32x4 cacc[8];
#pragma unroll
    for (int i = 0; i < 8; i++) {
        f32x4 z = {0.f, 0.f, 0.f, 0.f};
        cacc[i] = z;
    }

    // t = 0: h == 0, only the x/bias K-step contributes
    run_step<16, true>(buf0, buf1, Wt, cacc, wave, lane);
    xfill(buf1, xlds, 1, tid);
    __syncthreads();

    for (int t = 1; t < 4; t++) {
        _Float16* cur = (t & 1) ? buf1 : buf0;
        _Float16* nxt = (t & 1) ? buf0 : buf1;
        run_step<0, true>(cur, nxt, Wt, cacc, wave, lane);
        xfill(nxt, xlds, t + 1, tid);
        __syncthreads();
    }
    // t = 4: no h write needed
    run_step<0, false>(buf0, buf1, Wt, cacc, wave, lane);

    // write final c
    const int c = lane & 15, kq = lane >> 4;
#pragma unroll
    for (int ji = 0; ji < 2; ji++) {
        const int j = wave * 2 + ji;
#pragma unroll
        for (int rt = 0; rt < 4; rt++) {
            f32x4 cv = cacc[ji * 4 + rt];
#pragma unroll
            for (int r = 0; r < 4; r++)
                out[(size_t)(b0 + rt * 16 + kq * 4 + r) * HID + j * 16 + c] = cv[r];
        }
    }
}

extern "C" void kernel_launch(void* const* d_in, const int* in_sizes, int n_in,
                              void* d_out, int out_size, void* d_ws, size_t ws_size,
                              hipStream_t stream) {
    const float* ts  = (const float*)d_in[0];
    const float* Wih = (const float*)d_in[1];
    const float* Whh = (const float*)d_in[2];
    const float* bih = (const float*)d_in[3];
    const float* bhh = (const float*)d_in[4];
    float* out       = (float*)d_out;
    _Float16* Wt     = (_Float16*)d_ws;   // 2176 frags x 1 KB = 2,228,224 B

    (void)in_sizes; (void)n_in; (void)out_size; (void)ws_size;

    hipFuncSetAttribute(reinterpret_cast<const void*>(lstm_main),
                        hipFuncAttributeMaxDynamicSharedMemorySize, SMEM_BYTES);

    pack_w<<<544, 256, 0, stream>>>(Wih, Whh, bih, bhh, Wt);
    lstm_main<<<256, NTHR, SMEM_BYTES, stream>>>(ts, Wt, out);
}

// Round 9
// 212.629 us; speedup vs baseline: 1.5914x; 1.2314x over previous
//
#include <hip/hip_runtime.h>
#include <hip/hip_bf16.h>

// LSTM: B=16384, T=5, IN=11, H=512. Output = final cell state c [B,H] fp32.
//
// R9: back to single-pass over gates (A-frag read ONCE per trip -> LDS pipe
// ~44us instead of R8's ~87us) with a register diet so it fits 64 arch regs
// (R6 tried this shape and spilled ~5 regs):
//  - B loads in saddr form: wave-uniform SGPR base (readfirstlane, stepped
//    with s_add) + one lane*16 voffset + imm offsets g*1024 -> 1 VGPR total.
//  - epilogue: W/bias pre-scaled by log2e (2*log2e for gate g) in pack_w so
//    gates are exp2-ready; v_exp_f32 + v_rcp_f32 with fused denominators --
//    no v_div expansions, fewer temps. sig(i)*tanh(g) and sig(o)*tanh(c)
//    each cost 2 exp + 1 rcp.
//  - acc[4][4] (64) in AGPRs; cacc 32 + B 16 + A 4 + addr 2 ~= 60 arch.
//  - kept: 16 waves (4/SIMD), frag-ordered h (conflict-free ds_read_b128),
//    `#pragma unroll 1` K-loop, W read exactly once per block per step.

#define HID   512
#define KSN   17                    // K = 544 = 512 h + 11 x + 1 bias + 20 pad
#define ROWS  64
#define NTHR  1024                  // 16 waves
#define HB    (KSN * 4 * 64 * 8)    // halves per frag-ordered h buffer = 34816
#define SMEM_HALFS (2 * HB + 64 * 56)
#define SMEM_BYTES (SMEM_HALFS * 2) // 146432 B -> 1 block/CU

#define L2E   1.442695041f
#define L2E2  2.885390082f

typedef _Float16 f16x8 __attribute__((ext_vector_type(8)));
typedef float f32x4 __attribute__((ext_vector_type(4)));

// ---------------- prologue: pack W into B-fragment-ordered fp16 tiles -------
// Fragment f = (j*KSN + ks)*4 + g, torch gate order (i,f,g,o). Lane l holds
// W[col = g*512 + j*16 + (l&15)][k = ks*32 + (l>>4)*8 .. +7], 16 B/lane.
// Columns pre-scaled: gates i,f,o by log2e; gate g by 2*log2e (exp2-ready).
__global__ void pack_w(const float* __restrict__ Wih, const float* __restrict__ Whh,
                       const float* __restrict__ bih, const float* __restrict__ bhh,
                       _Float16* __restrict__ Wt) {
    int tid  = blockIdx.x * 256 + threadIdx.x;
    int frag = tid >> 6;
    int lane = tid & 63;
    if (frag >= 32 * KSN * 4) return;
    int g  = frag & 3;
    int ks = (frag >> 2) % KSN;
    int j  = frag / (4 * KSN);
    int col = g * 512 + j * 16 + (lane & 15);
    int kb  = ks * 32 + ((lane >> 4) << 3);
    float scale = (g == 2) ? L2E2 : L2E;
    _Float16 v[8];
#pragma unroll
    for (int q = 0; q < 8; q++) {
        int k = kb + q;
        float x;
        if (k < 512)      x = Whh[col * 512 + k];
        else if (k < 523) x = Wih[col * 11 + (k - 512)];
        else if (k == 523) x = bih[col] + bhh[col];
        else              x = 0.0f;
        v[q] = (_Float16)(x * scale);
    }
    *(f16x8*)(Wt + (size_t)frag * 512 + lane * 8) = *(const f16x8*)v;
}

// ---------------- one recurrent step ----------------------------------------
// Wave w: 64 rows (rt 0..3), col-quads j = 2w+ji (ji 0..1), all 4 gates.
// h buffers A-frag ordered: f16x8 unit index = (ks*4 + rt)*64 + lane.
template <int KS0, bool WRITE_H>
__device__ __forceinline__ void run_step(const _Float16* __restrict__ cur,
                                         _Float16* __restrict__ nxt,
                                         const char* __restrict__ wbase, // uniform
                                         f32x4* __restrict__ cacc,
                                         const int wave, const int lane) {
    const int c  = lane & 15;
    const int kq = lane >> 4;
    const int lane16 = lane * 16;                 // voffset for B saddr loads
#pragma unroll
    for (int ji = 0; ji < 2; ji++) {
        const int jj = __builtin_amdgcn_readfirstlane(wave * 2 + ji); // SGPR j
        const char* __restrict__ wjs = wbase + (size_t)jj * (KSN * 4096)
                                             + (size_t)KS0 * 4096;    // SGPR base
        const char* __restrict__ ac = (const char*)cur + KS0 * 4096 + lane16;

        f32x4 acc[4][4];                          // [row-tile][gate] -> AGPR
#pragma unroll
        for (int rt = 0; rt < 4; rt++)
#pragma unroll
            for (int g = 0; g < 4; g++) {
                f32x4 z = {0.f, 0.f, 0.f, 0.f};
                acc[rt][g] = z;
            }

#pragma unroll 1                                  // REAL loop (anti-spill)
        for (int ks = KS0; ks < KSN; ks++) {
            f16x8 B0 = *(const f16x8*)(wjs + lane16 + 0);
            f16x8 B1 = *(const f16x8*)(wjs + lane16 + 1024);
            f16x8 B2 = *(const f16x8*)(wjs + lane16 + 2048);
            f16x8 B3 = *(const f16x8*)(wjs + lane16 + 3072);
#pragma unroll
            for (int rt = 0; rt < 4; rt++) {
                f16x8 A = *(const f16x8*)(ac + rt * 1024);  // one A at a time
                acc[rt][0] = __builtin_amdgcn_mfma_f32_16x16x32_f16(A, B0, acc[rt][0], 0, 0, 0);
                acc[rt][1] = __builtin_amdgcn_mfma_f32_16x16x32_f16(A, B1, acc[rt][1], 0, 0, 0);
                acc[rt][2] = __builtin_amdgcn_mfma_f32_16x16x32_f16(A, B2, acc[rt][2], 0, 0, 0);
                acc[rt][3] = __builtin_amdgcn_mfma_f32_16x16x32_f16(A, B3, acc[rt][3], 0, 0, 0);
            }
            wjs += 4096;                          // s_add (uniform)
            ac  += 4096;                          // v_add (LDS addr)
        }

        // epilogue: gates are exp2-ready (pre-scaled by log2e / 2log2e).
        // C/D layout: col = lane&15, row = (lane>>4)*4 + r.
        const int j = wave * 2 + ji;
        _Float16* __restrict__ hw = nxt + (j >> 1) * 2048
            + (kq * 4 + 16 * (((j & 1) << 1) | (c >> 3))) * 8 + (c & 7);
#pragma unroll
        for (int rt = 0; rt < 4; rt++) {
            f32x4 cv = cacc[ji * 4 + rt];
#pragma unroll
            for (int r = 0; r < 4; r++) {
                float ai = acc[rt][0][r];         // i * log2e
                float af = acc[rt][1][r];         // f * log2e
                float ag = acc[rt][2][r];         // 2g * log2e
                float ao = acc[rt][3][r];         // o * log2e
                float ei = __builtin_amdgcn_exp2f(-ai);
                float eg = __builtin_amdgcn_exp2f(ag);
                // sig(i)*tanh(g) = (eg-1) / ((1+ei)*(1+eg))
                float ig = (eg - 1.0f) *
                           __builtin_amdgcn_rcpf((1.0f + ei) * (1.0f + eg));
                float ef = __builtin_amdgcn_exp2f(-af);
                float cn = __builtin_amdgcn_rcpf(1.0f + ef) * cv[r] + ig;
                cv[r] = cn;
                if (WRITE_H) {
                    float eo = __builtin_amdgcn_exp2f(-ao);
                    float ec = __builtin_amdgcn_exp2f(cn * L2E2);
                    float hn = (ec - 1.0f) *
                               __builtin_amdgcn_rcpf((1.0f + eo) * (1.0f + ec));
                    hw[rt * 512 + r * 8] = (_Float16)hn;
                }
            }
            cacc[ji * 4 + rt] = cv;
        }
    }
}

// x_t (11 elems) into the ks=16 frag region of a buffer (A-frag layout).
__device__ __forceinline__ void xfill(_Float16* __restrict__ nxt,
                                      const _Float16* __restrict__ xlds,
                                      int step, int tid) {
    for (int i = tid; i < 64 * 11; i += NTHR) {
        int row = i / 11, xi = i - row * 11;
        int idx = ((16 * 4 + (row >> 4)) * 64 + ((row & 15) + 16 * (xi >> 3))) * 8
                  + (xi & 7);
        nxt[idx] = xlds[row * 56 + step * 11 + xi];
    }
}

// ---------------- main persistent kernel ------------------------------------
__global__ __launch_bounds__(NTHR, 4)
void lstm_main(const float* __restrict__ ts,
               const _Float16* __restrict__ Wt,
               float* __restrict__ out) {
    extern __shared__ _Float16 smem[];
    _Float16* buf0 = smem;             // frag-ordered h buffers
    _Float16* buf1 = smem + HB;
    _Float16* xlds = smem + 2 * HB;    // [64][56] fp16 staged ts rows
    const int tid  = threadIdx.x;
    const int lane = tid & 63;
    const int wave = tid >> 6;         // 0..15
    const int b0   = blockIdx.x * ROWS;
    const char* wbase = (const char*)Wt;

    // zero both h buffers (covers all pad columns)
    {
        f16x8 z = {(_Float16)0, (_Float16)0, (_Float16)0, (_Float16)0,
                   (_Float16)0, (_Float16)0, (_Float16)0, (_Float16)0};
        for (int i = tid * 8; i < 2 * HB; i += NTHR * 8)
            *(f16x8*)(smem + i) = z;
    }
    // stage this block's time_series rows (coalesced) as fp16
    for (int i = tid; i < 64 * 55; i += NTHR) {
        int row = i / 55, e = i - row * 55;
        xlds[row * 56 + e] = (_Float16)ts[(size_t)(b0 + row) * 55 + e];
    }
    __syncthreads();
    // bias column (k=523 -> ks16, kq2=1, q=3) = 1.0 in both buffers; x_0 -> buf0
    if (tid < 128) {
        int bsel = tid >> 6, row = tid & 63;
        int idx = ((16 * 4 + (row >> 4)) * 64 + ((row & 15) + 16)) * 8 + 3;
        (bsel ? buf1 : buf0)[idx] = (_Float16)1.0f;
    }
    xfill(buf0, xlds, 0, tid);
    __syncthreads();

    f32x4 cacc[8];
#pragma unroll
    for (int i = 0; i < 8; i++) {
        f32x4 z = {0.f, 0.f, 0.f, 0.f};
        cacc[i] = z;
    }

    // t = 0: h == 0, only the x/bias K-step contributes
    run_step<16, true>(buf0, buf1, wbase, cacc, wave, lane);
    xfill(buf1, xlds, 1, tid);
    __syncthreads();

    for (int t = 1; t < 4; t++) {
        _Float16* cur = (t & 1) ? buf1 : buf0;
        _Float16* nxt = (t & 1) ? buf0 : buf1;
        run_step<0, true>(cur, nxt, wbase, cacc, wave, lane);
        xfill(nxt, xlds, t + 1, tid);
        __syncthreads();
    }
    // t = 4: no h write needed
    run_step<0, false>(buf0, buf1, wbase, cacc, wave, lane);

    // write final c
    const int c = lane & 15, kq = lane >> 4;
#pragma unroll
    for (int ji = 0; ji < 2; ji++) {
        const int j = wave * 2 + ji;
#pragma unroll
        for (int rt = 0; rt < 4; rt++) {
            f32x4 cv = cacc[ji * 4 + rt];
#pragma unroll
            for (int r = 0; r < 4; r++)
                out[(size_t)(b0 + rt * 16 + kq * 4 + r) * HID + j * 16 + c] = cv[r];
        }
    }
}

extern "C" void kernel_launch(void* const* d_in, const int* in_sizes, int n_in,
                              void* d_out, int out_size, void* d_ws, size_t ws_size,
                              hipStream_t stream) {
    const float* ts  = (const float*)d_in[0];
    const float* Wih = (const float*)d_in[1];
    const float* Whh = (const float*)d_in[2];
    const float* bih = (const float*)d_in[3];
    const float* bhh = (const float*)d_in[4];
    float* out       = (float*)d_out;
    _Float16* Wt     = (_Float16*)d_ws;   // 2176 frags x 1 KB = 2,228,224 B

    (void)in_sizes; (void)n_in; (void)out_size; (void)ws_size;

    hipFuncSetAttribute(reinterpret_cast<const void*>(lstm_main),
                        hipFuncAttributeMaxDynamicSharedMemorySize, SMEM_BYTES);

    pack_w<<<544, 256, 0, stream>>>(Wih, Whh, bih, bhh, Wt);
    lstm_main<<<256, NTHR, SMEM_BYTES, stream>>>(ts, Wt, out);
}

// Round 10
// 205.984 us; speedup vs baseline: 1.6427x; 1.0323x over previous
//
#include <hip/hip_runtime.h>
#include <hip/hip_bf16.h>

// LSTM: B=16384, T=5, IN=11, H=512. Output = final cell state c [B,H] fp32.
//
// R10: lstm_main is UNCHANGED from R9 (145 us, MfmaUtil 46%, spill-free).
// The fix this round is pack_w: every round's bench dur exceeded the
// lstm_main dispatch by ~50-67 us -- that was pack_w's uncoalesced reads
// (lane-adjacent addresses 2 KB apart -> 64 cachelines/instr, ~2 waves/CU).
// New pack_w: one WAVE per output column; lane l reads Whh[col*512+l*8..+7]
// -> each wave reads one contiguous 2 KB row fully coalesced (2 dwordx4 per
// lane), scales by log2e (2log2e for gate g), stores one f16x8 straight into
// fragment order. x/bias tail (ks=16) done by lanes 0..3.

#define HID   512
#define KSN   17                    // K = 544 = 512 h + 11 x + 1 bias + 20 pad
#define ROWS  64
#define NTHR  1024                  // 16 waves
#define HB    (KSN * 4 * 64 * 8)    // halves per frag-ordered h buffer = 34816
#define SMEM_HALFS (2 * HB + 64 * 56)
#define SMEM_BYTES (SMEM_HALFS * 2) // 146432 B -> 1 block/CU

#define L2E   1.442695041f
#define L2E2  2.885390082f

typedef _Float16 f16x8 __attribute__((ext_vector_type(8)));
typedef float f32x4 __attribute__((ext_vector_type(4)));

// ---------------- prologue: pack W into B-fragment-ordered fp16 tiles -------
// Fragment f = (j*KSN + ks)*4 + g, torch gate order (i,f,g,o). Lane l of the
// consuming wave holds W[col = g*512 + j*16 + (l&15)][k = ks*32 + (l>>4)*8..+7].
// Columns pre-scaled: gates i,f,o by log2e; gate g by 2*log2e (exp2-ready).
// One packing wave per column: coalesced 2 KB row read, f16x8 frag store.
__global__ __launch_bounds__(256) void pack_w(const float* __restrict__ Wih,
                                              const float* __restrict__ Whh,
                                              const float* __restrict__ bih,
                                              const float* __restrict__ bhh,
                                              _Float16* __restrict__ Wt) {
    const int col  = blockIdx.x * 4 + (threadIdx.x >> 6);   // 0..2047
    const int lane = threadIdx.x & 63;
    const int g = col >> 9;
    const int j = (col & 511) >> 4;
    const int c = col & 15;
    const float scale = (g == 2) ? L2E2 : L2E;

    // main region: k = lane*8 .. +7 (h part, k<512) -- coalesced row read
    const float4* __restrict__ src = (const float4*)(Whh + (size_t)col * 512);
    float4 u0 = src[lane * 2 + 0];
    float4 u1 = src[lane * 2 + 1];
    _Float16 v[8];
    v[0] = (_Float16)(u0.x * scale);
    v[1] = (_Float16)(u0.y * scale);
    v[2] = (_Float16)(u0.z * scale);
    v[3] = (_Float16)(u0.w * scale);
    v[4] = (_Float16)(u1.x * scale);
    v[5] = (_Float16)(u1.y * scale);
    v[6] = (_Float16)(u1.z * scale);
    v[7] = (_Float16)(u1.w * scale);
    const int ks = lane >> 2, kq = lane & 3;
    const size_t frag = ((size_t)j * KSN + ks) * 4 + g;
    *(f16x8*)(Wt + frag * 512 + (c + 16 * kq) * 8) = *(const f16x8*)v;

    // tail region: ks=16 frag (x cols 512..522, bias 523, pad) by lanes 0..3
    if (lane < 4) {
        _Float16 w[8];
        const int kb = 512 + lane * 8;
#pragma unroll
        for (int q = 0; q < 8; q++) {
            int k = kb + q;
            float x;
            if (k < 523)       x = Wih[col * 11 + (k - 512)];
            else if (k == 523) x = bih[col] + bhh[col];
            else               x = 0.0f;
            w[q] = (_Float16)(x * scale);
        }
        const size_t fragt = ((size_t)j * KSN + 16) * 4 + g;
        *(f16x8*)(Wt + fragt * 512 + (c + 16 * lane) * 8) = *(const f16x8*)w;
    }
}

// ---------------- one recurrent step ----------------------------------------
// Wave w: 64 rows (rt 0..3), col-quads j = 2w+ji (ji 0..1), all 4 gates.
// h buffers A-frag ordered: f16x8 unit index = (ks*4 + rt)*64 + lane.
template <int KS0, bool WRITE_H>
__device__ __forceinline__ void run_step(const _Float16* __restrict__ cur,
                                         _Float16* __restrict__ nxt,
                                         const char* __restrict__ wbase, // uniform
                                         f32x4* __restrict__ cacc,
                                         const int wave, const int lane) {
    const int c  = lane & 15;
    const int kq = lane >> 4;
    const int lane16 = lane * 16;                 // voffset for B saddr loads
#pragma unroll
    for (int ji = 0; ji < 2; ji++) {
        const int jj = __builtin_amdgcn_readfirstlane(wave * 2 + ji); // SGPR j
        const char* __restrict__ wjs = wbase + (size_t)jj * (KSN * 4096)
                                             + (size_t)KS0 * 4096;    // SGPR base
        const char* __restrict__ ac = (const char*)cur + KS0 * 4096 + lane16;

        f32x4 acc[4][4];                          // [row-tile][gate] -> AGPR
#pragma unroll
        for (int rt = 0; rt < 4; rt++)
#pragma unroll
            for (int g = 0; g < 4; g++) {
                f32x4 z = {0.f, 0.f, 0.f, 0.f};
                acc[rt][g] = z;
            }

#pragma unroll 1                                  // REAL loop (anti-spill)
        for (int ks = KS0; ks < KSN; ks++) {
            f16x8 B0 = *(const f16x8*)(wjs + lane16 + 0);
            f16x8 B1 = *(const f16x8*)(wjs + lane16 + 1024);
            f16x8 B2 = *(const f16x8*)(wjs + lane16 + 2048);
            f16x8 B3 = *(const f16x8*)(wjs + lane16 + 3072);
#pragma unroll
            for (int rt = 0; rt < 4; rt++) {
                f16x8 A = *(const f16x8*)(ac + rt * 1024);  // one A at a time
                acc[rt][0] = __builtin_amdgcn_mfma_f32_16x16x32_f16(A, B0, acc[rt][0], 0, 0, 0);
                acc[rt][1] = __builtin_amdgcn_mfma_f32_16x16x32_f16(A, B1, acc[rt][1], 0, 0, 0);
                acc[rt][2] = __builtin_amdgcn_mfma_f32_16x16x32_f16(A, B2, acc[rt][2], 0, 0, 0);
                acc[rt][3] = __builtin_amdgcn_mfma_f32_16x16x32_f16(A, B3, acc[rt][3], 0, 0, 0);
            }
            wjs += 4096;                          // s_add (uniform)
            ac  += 4096;                          // v_add (LDS addr)
        }

        // epilogue: gates are exp2-ready (pre-scaled by log2e / 2log2e).
        // C/D layout: col = lane&15, row = (lane>>4)*4 + r.
        const int j = wave * 2 + ji;
        _Float16* __restrict__ hw = nxt + (j >> 1) * 2048
            + (kq * 4 + 16 * (((j & 1) << 1) | (c >> 3))) * 8 + (c & 7);
#pragma unroll
        for (int rt = 0; rt < 4; rt++) {
            f32x4 cv = cacc[ji * 4 + rt];
#pragma unroll
            for (int r = 0; r < 4; r++) {
                float ai = acc[rt][0][r];         // i * log2e
                float af = acc[rt][1][r];         // f * log2e
                float ag = acc[rt][2][r];         // 2g * log2e
                float ao = acc[rt][3][r];         // o * log2e
                float ei = __builtin_amdgcn_exp2f(-ai);
                float eg = __builtin_amdgcn_exp2f(ag);
                // sig(i)*tanh(g) = (eg-1) / ((1+ei)*(1+eg))
                float ig = (eg - 1.0f) *
                           __builtin_amdgcn_rcpf((1.0f + ei) * (1.0f + eg));
                float ef = __builtin_amdgcn_exp2f(-af);
                float cn = __builtin_amdgcn_rcpf(1.0f + ef) * cv[r] + ig;
                cv[r] = cn;
                if (WRITE_H) {
                    float eo = __builtin_amdgcn_exp2f(-ao);
                    float ec = __builtin_amdgcn_exp2f(cn * L2E2);
                    float hn = (ec - 1.0f) *
                               __builtin_amdgcn_rcpf((1.0f + eo) * (1.0f + ec));
                    hw[rt * 512 + r * 8] = (_Float16)hn;
                }
            }
            cacc[ji * 4 + rt] = cv;
        }
    }
}

// x_t (11 elems) into the ks=16 frag region of a buffer (A-frag layout).
__device__ __forceinline__ void xfill(_Float16* __restrict__ nxt,
                                      const _Float16* __restrict__ xlds,
                                      int step, int tid) {
    for (int i = tid; i < 64 * 11; i += NTHR) {
        int row = i / 11, xi = i - row * 11;
        int idx = ((16 * 4 + (row >> 4)) * 64 + ((row & 15) + 16 * (xi >> 3))) * 8
                  + (xi & 7);
        nxt[idx] = xlds[row * 56 + step * 11 + xi];
    }
}

// ---------------- main persistent kernel ------------------------------------
__global__ __launch_bounds__(NTHR, 4)
void lstm_main(const float* __restrict__ ts,
               const _Float16* __restrict__ Wt,
               float* __restrict__ out) {
    extern __shared__ _Float16 smem[];
    _Float16* buf0 = smem;             // frag-ordered h buffers
    _Float16* buf1 = smem + HB;
    _Float16* xlds = smem + 2 * HB;    // [64][56] fp16 staged ts rows
    const int tid  = threadIdx.x;
    const int lane = tid & 63;
    const int wave = tid >> 6;         // 0..15
    const int b0   = blockIdx.x * ROWS;
    const char* wbase = (const char*)Wt;

    // zero both h buffers (covers all pad columns)
    {
        f16x8 z = {(_Float16)0, (_Float16)0, (_Float16)0, (_Float16)0,
                   (_Float16)0, (_Float16)0, (_Float16)0, (_Float16)0};
        for (int i = tid * 8; i < 2 * HB; i += NTHR * 8)
            *(f16x8*)(smem + i) = z;
    }
    // stage this block's time_series rows (coalesced) as fp16
    for (int i = tid; i < 64 * 55; i += NTHR) {
        int row = i / 55, e = i - row * 55;
        xlds[row * 56 + e] = (_Float16)ts[(size_t)(b0 + row) * 55 + e];
    }
    __syncthreads();
    // bias column (k=523 -> ks16, kq2=1, q=3) = 1.0 in both buffers; x_0 -> buf0
    if (tid < 128) {
        int bsel = tid >> 6, row = tid & 63;
        int idx = ((16 * 4 + (row >> 4)) * 64 + ((row & 15) + 16)) * 8 + 3;
        (bsel ? buf1 : buf0)[idx] = (_Float16)1.0f;
    }
    xfill(buf0, xlds, 0, tid);
    __syncthreads();

    f32x4 cacc[8];
#pragma unroll
    for (int i = 0; i < 8; i++) {
        f32x4 z = {0.f, 0.f, 0.f, 0.f};
        cacc[i] = z;
    }

    // t = 0: h == 0, only the x/bias K-step contributes
    run_step<16, true>(buf0, buf1, wbase, cacc, wave, lane);
    xfill(buf1, xlds, 1, tid);
    __syncthreads();

    for (int t = 1; t < 4; t++) {
        _Float16* cur = (t & 1) ? buf1 : buf0;
        _Float16* nxt = (t & 1) ? buf0 : buf1;
        run_step<0, true>(cur, nxt, wbase, cacc, wave, lane);
        xfill(nxt, xlds, t + 1, tid);
        __syncthreads();
    }
    // t = 4: no h write needed
    run_step<0, false>(buf0, buf1, wbase, cacc, wave, lane);

    // write final c
    const int c = lane & 15, kq = lane >> 4;
#pragma unroll
    for (int ji = 0; ji < 2; ji++) {
        const int j = wave * 2 + ji;
#pragma unroll
        for (int rt = 0; rt < 4; rt++) {
            f32x4 cv = cacc[ji * 4 + rt];
#pragma unroll
            for (int r = 0; r < 4; r++)
                out[(size_t)(b0 + rt * 16 + kq * 4 + r) * HID + j * 16 + c] = cv[r];
        }
    }
}

extern "C" void kernel_launch(void* const* d_in, const int* in_sizes, int n_in,
                              void* d_out, int out_size, void* d_ws, size_t ws_size,
                              hipStream_t stream) {
    const float* ts  = (const float*)d_in[0];
    const float* Wih = (const float*)d_in[1];
    const float* Whh = (const float*)d_in[2];
    const float* bih = (const float*)d_in[3];
    const float* bhh = (const float*)d_in[4];
    float* out       = (float*)d_out;
    _Float16* Wt     = (_Float16*)d_ws;   // 2176 frags x 1 KB = 2,228,224 B

    (void)in_sizes; (void)n_in; (void)out_size; (void)ws_size;

    hipFuncSetAttribute(reinterpret_cast<const void*>(lstm_main),
                        hipFuncAttributeMaxDynamicSharedMemorySize, SMEM_BYTES);

    pack_w<<<512, 256, 0, stream>>>(Wih, Whh, bih, bhh, Wt);
    lstm_main<<<256, NTHR, SMEM_BYTES, stream>>>(ts, Wt, out);
}